// Round 1
// baseline (1946.408 us; speedup 1.0000x reference)
//
#include <hip/hip_runtime.h>
#include <vector>
#include <cmath>
#include <cstdint>

// ---------------- static model tables (constexpr, device-usable) ----------------
constexpr int KLc[4]  = {256,192,128,64};     // k_max per l
constexpr int NMLc[4] = {8,6,4,2};            // radial basis per l
constexpr int SHBc[5] = {0,1,4,9,16};         // sh split bases
constexpr int RBBc[5] = {0,8,14,18,20};       // rb split bases
constexpr int FBc[5]  = {0,256,832,1472,1920};// feats flat base per l  (sum (2l+1)*K[l])
constexpr int NCMB = 34, CGTOT = 3436, WTOT = 738, FTOT = 1920;

struct Combos { int l1[NCMB], l2[NCMB], L[NCMB], cgoff[NCMB], woff[NCMB], kk[NCMB]; };
constexpr Combos make_combos(){
  Combos c{}; int n=0, cg=0, w=0;
  for(int a=0;a<=3;a++)for(int b=0;b<=3;b++){
    int lo=a>b?a-b:b-a, hi=(a+b<3)?(a+b):3;
    for(int L=lo;L<=hi;L++){
      c.l1[n]=a; c.l2[n]=b; c.L[n]=L; c.cgoff[n]=cg; c.woff[n]=w;
      int mx=a>b?a:b; if(L>mx) mx=L; c.kk[n]=KLc[mx];          // TP truncation
      cg+=(2*a+1)*(2*b+1)*(2*L+1); w+=(2*b+1)*(2*L+1); n++;
    }
  }
  return c;
}
constexpr Combos CB = make_combos();
static_assert(CB.cgoff[NCMB-1] + 7*7*7 == CGTOT, "cg size");
static_assert(CB.woff[NCMB-1] + 7*7 == WTOT, "w size");

struct Grp { int cnt[4]; int list[4][12]; };
constexpr Grp make_Lg(){ Grp g{}; for(int i=0;i<NCMB;i++){ int L=CB.L[i]; g.list[L][g.cnt[L]++]=i; } return g; }
constexpr Grp LG = make_Lg();     // combos grouped by output L (for k_tp)
constexpr Grp make_l2g(){ Grp g{}; for(int i=0;i<NCMB;i++){ int l2=CB.l2[i]; g.list[l2][g.cnt[l2]++]=i; } return g; }
constexpr Grp L2G = make_l2g();   // combos grouped by l2 (for k_eq)

struct WMap { short ci[WTOT]; unsigned char b[WTOT]; unsigned char M[WTOT]; };
constexpr WMap make_wmap(){ WMap w{}; int e=0;
  for(int i=0;i<NCMB;i++){ int n2=2*CB.l2[i]+1, nL=2*CB.L[i]+1;
    for(int b=0;b<n2;b++)for(int M=0;M<nL;M++){ w.ci[e]=(short)i; w.b[e]=(unsigned char)b; w.M[e]=(unsigned char)M; e++; } }
  return w; }
constexpr WMap WM = make_wmap();

struct Rows { int sh[64], rb[64], off[64]; };
constexpr Rows make_rows(){ Rows r{}; int i=0;
  for(int l=0;l<4;l++)for(int m=0;m<2*l+1;m++)for(int n=0;n<NMLc[l];n++){
    r.sh[i]=SHBc[l]+m; r.rb[i]=RBBc[l]+n; r.off[i]=FBc[l]+m*KLc[l]+n*32; i++; }
  for(;i<64;i++){ r.sh[i]=0; r.rb[i]=0; r.off[i]=0; }
  return r; }
constexpr Rows RWS = make_rows();  // 60 (l,m,n) rows for invariant MP

// ---------------- host: numpy-legacy RandomState(0) CG generation ----------------
namespace nprng {
struct MT {
  uint32_t mt[624]; int mti; bool has_g; double g;
  void seed(uint32_t s){ for(int i=0;i<624;i++){ mt[i]=s; s=1812433253u*(s^(s>>30))+(uint32_t)i+1u; } mti=624; has_g=false; g=0.0; }
  uint32_t u32(){
    if(mti>=624){
      for(int i=0;i<624;i++){
        uint32_t y=(mt[i]&0x80000000u)|(mt[(i+1)%624]&0x7fffffffu);
        mt[i]=mt[(i+397)%624]^(y>>1)^((y&1u)?0x9908b0dfu:0u);
      }
      mti=0;
    }
    uint32_t y=mt[mti++];
    y^=y>>11; y^=(y<<7)&0x9d2c5680u; y^=(y<<15)&0xefc60000u; y^=y>>18;
    return y;
  }
  double dbl(){ uint32_t a=u32()>>5, b=u32()>>6; return (a*67108864.0+b)/9007199254740992.0; }
  double gauss(){
    if(has_g){ has_g=false; return g; }
    double f,x1,x2,r2;
    do{ x1=2.0*dbl()-1.0; x2=2.0*dbl()-1.0; r2=x1*x1+x2*x2; }while(r2>=1.0||r2==0.0);
    f=sqrt(-2.0*log(r2)/r2);
    g=f*x1; has_g=true; return f*x2;
  }
};
}
static std::vector<float> build_cg(){
  nprng::MT r; r.seed(0);
  std::vector<float> v; v.reserve(CGTOT);
  for(int l1=0;l1<=3;l1++)for(int l2=0;l2<=3;l2++){
    int lo = l1>l2? l1-l2 : l2-l1;
    int hi = (l1+l2<3)? (l1+l2) : 3;
    for(int L=lo;L<=hi;L++){
      int n=(2*l1+1)*(2*l2+1)*(2*L+1);
      for(int i=0;i<n;i++) v.push_back((float)(r.gauss()*0.2));
    }
  }
  return v;
}

// ---------------- kernels ----------------

// center_emb[n,c] = emb_table[species[n], c]; also zero the histogram counts
__global__ __launch_bounds__(256) void k_cemb(const float* __restrict__ emb_table,
    const int* __restrict__ species, float* __restrict__ cemb, int* __restrict__ counts, int N){
  int i = blockIdx.x*256 + threadIdx.x;
  if(i < N) counts[i] = 0;
  if(i < N*32){ int n = i>>5, c = i&31; cemb[i] = emb_table[species[n]*32 + c]; }
}

__global__ __launch_bounds__(256) void k_hist(const int* __restrict__ centers, int* counts, int P){
  int i = blockIdx.x*256 + threadIdx.x;
  if(i < P) atomicAdd(&counts[centers[i]], 1);
}

// single-block exclusive scan over N counts -> offsets (N+1) and cursor (N)
__global__ __launch_bounds__(256) void k_scan(const int* __restrict__ counts,
    int* __restrict__ offsets, int* __restrict__ cursor, int N){
  __shared__ int part[256];
  const int t = threadIdx.x;
  const int CH = (N + 255)/256;
  const int lo = t*CH;
  int hi = (t+1)*CH; if(hi > N) hi = N;
  int s = 0;
  for(int i=lo;i<hi;i++) s += counts[i];
  part[t] = s; __syncthreads();
  const int own = s;
  for(int d=1; d<256; d<<=1){
    int v = (t>=d)? part[t-d] : 0;
    __syncthreads();
    part[t] += v;
    __syncthreads();
  }
  int run = part[t] - own;
  for(int i=lo;i<hi;i++){ offsets[i]=run; cursor[i]=run; run += counts[i]; }
  if(t==255) offsets[N] = part[255];
}

__global__ __launch_bounds__(256) void k_scatter(const int* __restrict__ centers,
    int* cursor, int* __restrict__ perm, int P){
  int i = blockIdx.x*256 + threadIdx.x;
  if(i < P){ int c = centers[i]; int pos = atomicAdd(&cursor[c], 1); perm[pos] = i; }
}

// invariant MP: feats[a,(l,m,n),c] = 0.1 * sum_pairs (0.1*sh[l,m]) * rb[l,n] * emb_nbr[c]
__global__ __launch_bounds__(256) void k_inv(const float* __restrict__ sh, const float* __restrict__ rb,
    const float* __restrict__ cemb, const int* __restrict__ nbrs, const int* __restrict__ offsets,
    const int* __restrict__ perm, float* __restrict__ feats){
  const int a = blockIdx.x, t = threadIdx.x;
  __shared__ float sh_s[16], rb_s[20], emb_s[32], shrb[60];
  const int c = t & 31, rg = t >> 5;
  float acc[8];
  #pragma unroll
  for(int j=0;j<8;j++) acc[j] = 0.f;
  const int beg = offsets[a], end = offsets[a+1];
  for(int ip=beg; ip<end; ip++){
    const int p = perm[ip];
    if(t < 16)            sh_s[t]    = sh[p*16 + t] * 0.1f;         // NU_SCALING
    else if(t < 36)       rb_s[t-16] = rb[p*20 + (t-16)];
    else if(t < 68)       { int nb = nbrs[p]; emb_s[t-36] = cemb[(size_t)nb*32 + (t-36)]; }
    __syncthreads();
    if(t < 60) shrb[t] = sh_s[RWS.sh[t]] * rb_s[RWS.rb[t]];
    __syncthreads();
    const float e = emb_s[c];
    #pragma unroll
    for(int j=0;j<8;j++){ int r = rg + 8*j; if(r < 60) acc[j] += shrb[r]*e; }
    __syncthreads();
  }
  #pragma unroll
  for(int j=0;j<8;j++){
    int r = rg + 8*j;
    if(r < 60) feats[(size_t)a*FTOT + RWS.off[r] + c] = 0.1f * acc[j];  // MP_SCALING
  }
}

// CG iterate (in-place): feats = feats + 0.1 * TP(feats, feats)
__global__ __launch_bounds__(256) void k_tp(float* __restrict__ feats, const float* __restrict__ cg){
  const int a = blockIdx.x, t = threadIdx.x;
  __shared__ float f_s[FTOT];
  __shared__ float cg_s[CGTOT];
  float* fa = feats + (size_t)a*FTOT;
  for(int i=t;i<CGTOT;i+=256) cg_s[i] = cg[i];
  for(int i=t;i<FTOT;i+=256)  f_s[i]  = fa[i];
  __syncthreads();
  #pragma unroll
  for(int L=0; L<4; L++){
    const int KLL = KLc[L], nL = 2*L+1;
    const int nel = nL*KLL;
    for(int e=t; e<nel; e+=256){
      const int M = e / KLL, k = e - M*KLL;
      float acc = 0.f;
      #pragma unroll
      for(int gi=0; gi<LG.cnt[L]; gi++){
        const int ci = LG.list[L][gi];
        const int l1 = CB.l1[ci], l2 = CB.l2[ci];
        if(k < CB.kk[ci]){
          const int n2 = 2*l2+1;
          #pragma unroll
          for(int aa=0; aa<2*l1+1; aa++){
            const float Av = f_s[FBc[l1] + aa*KLc[l1] + k];
            #pragma unroll
            for(int b=0; b<n2; b++)
              acc += cg_s[CB.cgoff[ci] + (aa*n2+b)*nL + M] * (Av * f_s[FBc[l2] + b*KLc[l2] + k]);
          }
        }
      }
      fa[FBc[L] + M*KLL + k] = f_s[FBc[L] + M*KLL + k] + 0.1f*acc;   // NU_SCALING residual
    }
  }
}

// equivariant MP inner body for one l2 block (threads own (rep,k); no races within a call)
template<int L2>
__device__ inline void eq_l2_body(const int t, const int nb, const float* __restrict__ featsA,
    const float* __restrict__ w_s, float* __restrict__ mp_s, const float* __restrict__ emb_s){
  constexpr int K2 = KLc[L2], n2 = 2*L2+1, R = 256/K2;   // R: 1,1,2,4 (l2=1: 64 threads idle)
  const int rep = t / K2;
  if(rep >= R) return;
  const int k = t - rep*K2;
  float fg[n2];
  const float ec = emb_s[k & 31];                        // fused embed_centers on gathered nbr
  const float* src = featsA + (size_t)nb*FTOT + FBc[L2] + k;
  #pragma unroll
  for(int b=0;b<n2;b++) fg[b] = src[b*K2] * ec;
  #pragma unroll
  for(int gi=0; gi<L2G.cnt[L2]; gi++){
    const int ci = L2G.list[L2][gi];
    const int L  = CB.L[ci];
    const int nL = 2*L+1;
    const int kk = (K2 < KLc[L]) ? K2 : KLc[L];
    if(k < kk){
      const float* wp = w_s + CB.woff[ci];
      float* mpp = mp_s + FBc[L] + k;
      for(int M=rep; M<nL; M+=R){
        float acc = 0.f;
        #pragma unroll
        for(int b=0;b<n2;b++) acc += wp[b*nL + M] * fg[b];
        mpp[M*KLc[L]] += acc;
      }
    }
  }
}

__global__ __launch_bounds__(256) void k_eq(const float* __restrict__ sh, const float* __restrict__ rb,
    const float* __restrict__ cemb, const int* __restrict__ nbrs, const int* __restrict__ offsets,
    const int* __restrict__ perm, const float* __restrict__ featsA, float* __restrict__ featsB,
    const float* __restrict__ cg){
  const int a = blockIdx.x, t = threadIdx.x;
  __shared__ float cg_s[CGTOT];
  __shared__ float w_s[WTOT];
  __shared__ float mp_s[FTOT];
  __shared__ float edge_s[16];
  __shared__ float emb_s[32];
  for(int i=t;i<CGTOT;i+=256) cg_s[i] = cg[i];
  for(int i=t;i<FTOT;i+=256)  mp_s[i] = 0.f;
  __syncthreads();
  const int beg = offsets[a], end = offsets[a+1];
  for(int ip=beg; ip<end; ip++){
    const int p = perm[ip];
    const int nb = nbrs[p];
    if(t < 16){
      const int l = (t==0)?0 : (t<4)?1 : (t<9)?2 : 3;
      float s = 0.f;
      for(int n=RBBc[l]; n<RBBc[l+1]; n++) s += rb[p*20 + n];
      edge_s[t] = sh[p*16 + t] * 0.1f * s;               // sh * NU_SCALING * rb.sum
    } else if(t >= 32 && t < 64){
      emb_s[t-32] = cemb[(size_t)nb*32 + (t-32)];
    }
    __syncthreads();
    // w[b,M] = sum_a edge[l1,a] * cg[a,b,M]  (flat layout woff + b*nL + M)
    for(int e=t; e<WTOT; e+=256){
      const int ci = WM.ci[e], b = WM.b[e], M = WM.M[e];
      const int l1 = CB.l1[ci];
      const int n2 = 2*CB.l2[ci]+1, nL = 2*CB.L[ci]+1;
      float s = 0.f;
      for(int aa=0; aa<2*l1+1; aa++)
        s += edge_s[SHBc[l1]+aa] * cg_s[CB.cgoff[ci] + (aa*n2+b)*nL + M];
      w_s[e] = s;
    }
    __syncthreads();
    eq_l2_body<0>(t, nb, featsA, w_s, mp_s, emb_s); __syncthreads();
    eq_l2_body<1>(t, nb, featsA, w_s, mp_s, emb_s); __syncthreads();
    eq_l2_body<2>(t, nb, featsA, w_s, mp_s, emb_s); __syncthreads();
    eq_l2_body<3>(t, nb, featsA, w_s, mp_s, emb_s); __syncthreads();
  }
  float* out = featsB + (size_t)a*FTOT;
  for(int i=t;i<FTOT;i+=256) out[i] = 0.1f * mp_s[i];    // MP_SCALING
}

// energy: out[a] = sum_k feats[a,0,k]*cemb[a,k%32]*wE[k] + bE  (wave per atom)
__global__ __launch_bounds__(256) void k_energy(const float* __restrict__ feats,
    const float* __restrict__ cemb, const float* __restrict__ wE, const float* __restrict__ bE,
    float* __restrict__ out, int N){
  const int wid = threadIdx.x >> 6, lane = threadIdx.x & 63;
  const int a = blockIdx.x*4 + wid;
  if(a >= N) return;
  const float e = cemb[(size_t)a*32 + (lane & 31)];
  float s = 0.f;
  for(int k=lane; k<256; k+=64) s += feats[(size_t)a*FTOT + k] * e * wE[k];
  #pragma unroll
  for(int off=32; off; off>>=1) s += __shfl_down(s, off, 64);
  if(lane == 0) out[a] = s + bE[0];
}

// ---------------- launcher ----------------
extern "C" void kernel_launch(void* const* d_in, const int* in_sizes, int n_in,
                              void* d_out, int out_size, void* d_ws, size_t ws_size,
                              hipStream_t stream){
  const float* sh        = (const float*)d_in[0];
  const float* rb        = (const float*)d_in[1];
  const float* emb_table = (const float*)d_in[2];
  const float* wE        = (const float*)d_in[3];
  const float* bE        = (const float*)d_in[4];
  const int*   species   = (const int*)d_in[5];
  const int*   centers   = (const int*)d_in[6];
  const int*   nbrs      = (const int*)d_in[7];
  const int N = in_sizes[5];
  const int P = in_sizes[6];

  char* ws = (char*)d_ws; size_t off = 0;
  auto carve = [&](size_t bytes)->void*{
    void* p = ws + off; off = (off + bytes + 255) & ~(size_t)255; return p;
  };
  float* cg_d    = (float*)carve((size_t)CGTOT*4);
  float* cemb    = (float*)carve((size_t)N*32*4);
  int*   counts  = (int*)  carve((size_t)N*4);
  int*   offsets = (int*)  carve((size_t)(N+1)*4);
  int*   cursor  = (int*)  carve((size_t)N*4);
  int*   perm    = (int*)  carve((size_t)P*4);
  float* featsA  = (float*)carve((size_t)N*FTOT*4);
  float* featsB  = (float*)carve((size_t)N*FTOT*4);
  (void)ws_size; (void)n_in; (void)out_size;

  static const std::vector<float> cg_host = build_cg();  // deterministic; host-side cache only
  hipMemcpyAsync(cg_d, cg_host.data(), (size_t)CGTOT*4, hipMemcpyHostToDevice, stream);

  k_cemb   <<<(N*32 + 255)/256, 256, 0, stream>>>(emb_table, species, cemb, counts, N);
  k_hist   <<<(P + 255)/256,    256, 0, stream>>>(centers, counts, P);
  k_scan   <<<1,                256, 0, stream>>>(counts, offsets, cursor, N);
  k_scatter<<<(P + 255)/256,    256, 0, stream>>>(centers, cursor, perm, P);
  k_inv    <<<N,                256, 0, stream>>>(sh, rb, cemb, nbrs, offsets, perm, featsA);
  k_tp     <<<N,                256, 0, stream>>>(featsA, cg_d);
  k_eq     <<<N,                256, 0, stream>>>(sh, rb, cemb, nbrs, offsets, perm, featsA, featsB, cg_d);
  k_tp     <<<N,                256, 0, stream>>>(featsB, cg_d);
  k_energy <<<(N + 3)/4,        256, 0, stream>>>(featsB, cemb, wE, bE, (float*)d_out, N);
}

// Round 2
// 965.398 us; speedup vs baseline: 2.0162x; 2.0162x over previous
//
#include <hip/hip_runtime.h>
#include <vector>
#include <cmath>
#include <cstdint>

// ---------------- static model tables (constexpr, device-usable) ----------------
constexpr int KLc[4]  = {256,192,128,64};     // k_max per l
constexpr int NMLc[4] = {8,6,4,2};            // radial basis per l
constexpr int SHBc[5] = {0,1,4,9,16};         // sh split bases
constexpr int RBBc[5] = {0,8,14,18,20};       // rb split bases
constexpr int FBc[5]  = {0,256,832,1472,1920};// feats flat base per l  (sum (2l+1)*K[l])
constexpr int NCMB = 34, CGTOT = 3436, FTOT = 1920;

struct Combos { int l1[NCMB], l2[NCMB], L[NCMB], cgoff[NCMB], kk[NCMB]; };
constexpr Combos make_combos(){
  Combos c{}; int n=0, cg=0;
  for(int a=0;a<=3;a++)for(int b=0;b<=3;b++){
    int lo=a>b?a-b:b-a, hi=(a+b<3)?(a+b):3;
    for(int L=lo;L<=hi;L++){
      c.l1[n]=a; c.l2[n]=b; c.L[n]=L; c.cgoff[n]=cg;
      int mx=a>b?a:b; if(L>mx) mx=L; c.kk[n]=KLc[mx];          // TP truncation (min of all three)
      cg+=(2*a+1)*(2*b+1)*(2*L+1); n++;
    }
  }
  return c;
}
constexpr Combos CB = make_combos();
static_assert(CB.cgoff[NCMB-1] + 7*7*7 == CGTOT, "cg size");

struct Grp { int cnt[4]; int list[4][12]; };
constexpr Grp make_Lg(){ Grp g{}; for(int i=0;i<NCMB;i++){ int L=CB.L[i]; g.list[L][g.cnt[L]++]=i; } return g; }
constexpr Grp LG = make_Lg();     // combos grouped by output L (for k_tp)

struct Rows { int sh[64], rb[64], off[64]; };
constexpr Rows make_rows(){ Rows r{}; int i=0;
  for(int l=0;l<4;l++)for(int m=0;m<2*l+1;m++)for(int n=0;n<NMLc[l];n++){
    r.sh[i]=SHBc[l]+m; r.rb[i]=RBBc[l]+n; r.off[i]=FBc[l]+m*KLc[l]+n*32; i++; }
  for(;i<64;i++){ r.sh[i]=0; r.rb[i]=0; r.off[i]=0; }
  return r; }
constexpr Rows RWS = make_rows();  // 60 (l,m,n) rows for invariant MP

// ---------------- k_eq v2 tables: S-factorization slices ----------------
// S[l1,a,l2,b][k] = sum_pairs edge[l1,a] * femb[l2,b,k]; slice unit = (l1,a,l2,b,ktile)
// Slice valid iff l2 <= 3-kt && |l1-l2| <= 3-kt   (equivariant kk = min(K[l2],K[L]), L>=|l1-l2|)
constexpr int NSL=425, MAXS=107, MAXR=12, RPAD=149; // RPAD odd -> 2-way bank aliasing (free)

constexpr int iabs_(int x){ return x<0?-x:x; }
__host__ __device__ constexpr bool sl_valid(int l1,int l2,int kt){ return l2<=3-kt && iabs_(l1-l2)<=3-kt; }

__host__ __device__ constexpr int rb_base(int kt,int l1,int l2){
  int base=0;
  for(int p=0;p<4;p++)for(int q=0;q<4;q++){
    if(p==l1 && q==l2) return base;
    if(sl_valid(p,q,kt)) base += (2*p+1)*(2*q+1);
  }
  return base;
}

struct EqTab {
  int ns[4];
  unsigned char eidx[4][MAXS];   // edge register index (SHB[l1]+a)
  unsigned char fidx[4][MAXS];   // fg register index within group
  short         srow[4][MAXS];   // stage row within its dump phase
  unsigned char sph [4][MAXS];   // dump phase 0..4
  int nr[4];
  short roff[4][MAXR];           // fg row offsets into feats (element units)
  int total;
};
constexpr EqTab make_eqtab(){
  EqTab T{}; int gidx=0;
  for(int l2=0;l2<4;l2++)for(int kt=0;kt<4-l2;kt++)for(int b=0;b<2*l2+1;b++){
    const int rowoff = FBc[l2] + b*KLc[l2] + kt*64;
    for(int l1=0;l1<4;l1++){
      if(!sl_valid(l1,l2,kt)) continue;
      for(int a=0;a<2*l1+1;a++){
        int g = (gidx*4)/NSL;
        int s = T.ns[g]++;
        T.eidx[g][s] = (unsigned char)(SHBc[l1]+a);
        int rbi = rb_base(kt,l1,l2) + a*(2*l2+1) + b;
        int ph, sr;
        if(kt==0){ if(l1<=2){ ph=0; sr=rbi; } else { ph=1; sr=rbi-144; } }
        else { ph=kt+1; sr=rbi; }
        T.sph[g][s]=(unsigned char)ph; T.srow[g][s]=(short)sr;
        int ri=-1;
        for(int r=0;r<T.nr[g];r++) if(T.roff[g][r]==(short)rowoff) ri=r;
        if(ri<0){ ri=T.nr[g]; T.roff[g][T.nr[g]++]=(short)rowoff; }
        T.fidx[g][s]=(unsigned char)ri;
        gidx++;
      }
    }
  }
  T.total=gidx;
  return T;
}
constexpr EqTab ET = make_eqtab();
static_assert(ET.total==NSL, "slice count");
static_assert(ET.ns[0]<=MAXS && ET.ns[1]<=MAXS && ET.ns[2]<=MAXS && ET.ns[3]<=MAXS, "MAXS");
static_assert(ET.nr[0]<=MAXR && ET.nr[1]<=MAXR && ET.nr[2]<=MAXR && ET.nr[3]<=MAXR, "MAXR");

// contraction combo -> group assignment (greedy by cost n1*n2*nL)
struct CAsg { int cnt[4]; unsigned char ci[4][16]; };
constexpr CAsg make_casg(){
  CAsg C{}; bool used[NCMB]{}; int load[4]{};
  for(int it=0; it<NCMB; it++){
    int best=-1, bc=-1;
    for(int i=0;i<NCMB;i++) if(!used[i]){
      int c=(2*CB.l1[i]+1)*(2*CB.l2[i]+1)*(2*CB.L[i]+1);
      if(c>bc){bc=c;best=i;}
    }
    used[best]=true;
    int g=0; for(int j=1;j<4;j++) if(load[j]<load[g]) g=j;
    C.ci[g][C.cnt[g]++]=(unsigned char)best; load[g]+=bc;
  }
  return C;
}
constexpr CAsg CA = make_casg();
static_assert(CA.cnt[0]<=16 && CA.cnt[1]<=16 && CA.cnt[2]<=16 && CA.cnt[3]<=16, "CA cap");

__host__ __device__ constexpr bool combo_in_phase(int ci,int ph){
  int l1=CB.l1[ci], l2=CB.l2[ci], L=CB.L[ci];
  if(ph==0) return l1<=2;
  if(ph==1) return l1==3;
  int kt=ph-1;
  return (l2<=3-kt) && (L<=3-kt);
}
__host__ __device__ constexpr int phase_kt(int ph){ return ph<=1?0:ph-1; }
__host__ __device__ constexpr int phase_rbadj(int ph){ return ph==1?144:0; }

// ---------------- host: numpy-legacy RandomState(0) CG generation ----------------
namespace nprng {
struct MT {
  uint32_t mt[624]; int mti; bool has_g; double g;
  void seed(uint32_t s){ for(int i=0;i<624;i++){ mt[i]=s; s=1812433253u*(s^(s>>30))+(uint32_t)i+1u; } mti=624; has_g=false; g=0.0; }
  uint32_t u32(){
    if(mti>=624){
      for(int i=0;i<624;i++){
        uint32_t y=(mt[i]&0x80000000u)|(mt[(i+1)%624]&0x7fffffffu);
        mt[i]=mt[(i+397)%624]^(y>>1)^((y&1u)?0x9908b0dfu:0u);
      }
      mti=0;
    }
    uint32_t y=mt[mti++];
    y^=y>>11; y^=(y<<7)&0x9d2c5680u; y^=(y<<15)&0xefc60000u; y^=y>>18;
    return y;
  }
  double dbl(){ uint32_t a=u32()>>5, b=u32()>>6; return (a*67108864.0+b)/9007199254740992.0; }
  double gauss(){
    if(has_g){ has_g=false; return g; }
    double f,x1,x2,r2;
    do{ x1=2.0*dbl()-1.0; x2=2.0*dbl()-1.0; r2=x1*x1+x2*x2; }while(r2>=1.0||r2==0.0);
    f=sqrt(-2.0*log(r2)/r2);
    g=f*x1; has_g=true; return f*x2;
  }
};
}
static std::vector<float> build_cg(){
  nprng::MT r; r.seed(0);
  std::vector<float> v; v.reserve(CGTOT);
  for(int l1=0;l1<=3;l1++)for(int l2=0;l2<=3;l2++){
    int lo = l1>l2? l1-l2 : l2-l1;
    int hi = (l1+l2<3)? (l1+l2) : 3;
    for(int L=lo;L<=hi;L++){
      int n=(2*l1+1)*(2*l2+1)*(2*L+1);
      for(int i=0;i<n;i++) v.push_back((float)(r.gauss()*0.2));
    }
  }
  return v;
}

// ---------------- small setup kernels ----------------
__global__ __launch_bounds__(256) void k_cemb(const float* __restrict__ emb_table,
    const int* __restrict__ species, float* __restrict__ cemb, int* __restrict__ counts, int N){
  int i = blockIdx.x*256 + threadIdx.x;
  if(i < N) counts[i] = 0;
  if(i < N*32){ int n = i>>5, c = i&31; cemb[i] = emb_table[species[n]*32 + c]; }
}

__global__ __launch_bounds__(256) void k_hist(const int* __restrict__ centers, int* counts, int P){
  int i = blockIdx.x*256 + threadIdx.x;
  if(i < P) atomicAdd(&counts[centers[i]], 1);
}

__global__ __launch_bounds__(256) void k_scan(const int* __restrict__ counts,
    int* __restrict__ offsets, int* __restrict__ cursor, int N){
  __shared__ int part[256];
  const int t = threadIdx.x;
  const int CH = (N + 255)/256;
  const int lo = t*CH;
  int hi = (t+1)*CH; if(hi > N) hi = N;
  int s = 0;
  for(int i=lo;i<hi;i++) s += counts[i];
  part[t] = s; __syncthreads();
  const int own = s;
  for(int d=1; d<256; d<<=1){
    int v = (t>=d)? part[t-d] : 0;
    __syncthreads();
    part[t] += v;
    __syncthreads();
  }
  int run = part[t] - own;
  for(int i=lo;i<hi;i++){ offsets[i]=run; cursor[i]=run; run += counts[i]; }
  if(t==255) offsets[N] = part[255];
}

__global__ __launch_bounds__(256) void k_scatter(const int* __restrict__ centers,
    int* cursor, int* __restrict__ perm, int P){
  int i = blockIdx.x*256 + threadIdx.x;
  if(i < P){ int c = centers[i]; int pos = atomicAdd(&cursor[c], 1); perm[pos] = i; }
}

// ---------------- invariant MP (batched pairs, 3 barriers / 8 pairs) ----------------
__global__ __launch_bounds__(256) void k_inv(const float* __restrict__ sh, const float* __restrict__ rb,
    const float* __restrict__ cemb, const int* __restrict__ nbrs, const int* __restrict__ offsets,
    const int* __restrict__ perm, float* __restrict__ feats){
  const int a = blockIdx.x, t = threadIdx.x;
  __shared__ float sh_s[8][16], rb_s[8][20], emb_s[8][32], shrb_s[8][60];
  const int c = t & 31, rg = t >> 5;
  float acc[8];
  #pragma unroll
  for(int j=0;j<8;j++) acc[j] = 0.f;
  const int beg = offsets[a], cnt = offsets[a+1]-beg;
  for(int jb=0; jb<cnt; jb+=8){
    __syncthreads();
    for(int u=t; u<8*36; u+=256){
      int j=u/36, i=u-36*j;
      if(jb+j<cnt){
        int p=perm[beg+jb+j];
        if(i<16) sh_s[j][i]=sh[p*16+i]*0.1f;      // NU_SCALING
        else     rb_s[j][i-16]=rb[p*20+i-16];
      }
    }
    for(int u=t; u<8*32; u+=256){
      int j=u>>5, i=u&31;
      if(jb+j<cnt){ int nb=nbrs[perm[beg+jb+j]]; emb_s[j][i]=cemb[(size_t)nb*32+i]; }
    }
    __syncthreads();
    for(int u=t; u<8*60; u+=256){
      int j=u/60, r=u-60*j;
      if(jb+j<cnt) shrb_s[j][r] = sh_s[j][RWS.sh[r]] * rb_s[j][RWS.rb[r]];
    }
    __syncthreads();
    const int jm = (cnt-jb<8)?(cnt-jb):8;
    for(int j=0;j<jm;j++){
      const float e = emb_s[j][c];
      #pragma unroll
      for(int q=0;q<8;q++){ int r=rg+8*q; if(r<60) acc[q]=fmaf(shrb_s[j][r], e, acc[q]); }
    }
  }
  #pragma unroll
  for(int q=0;q<8;q++){
    int r = rg + 8*q;
    if(r < 60) feats[(size_t)a*FTOT + RWS.off[r] + c] = 0.1f * acc[q];  // MP_SCALING
  }
}

// ---------------- CG iterate (in-place): feats = feats + 0.1 * TP(feats, feats) ----------------
__global__ __launch_bounds__(256) void k_tp(float* __restrict__ feats, const float* __restrict__ cg){
  const int a = blockIdx.x, t = threadIdx.x;
  __shared__ float f_s[FTOT];
  __shared__ float cg_s[CGTOT];
  float* fa = feats + (size_t)a*FTOT;
  for(int i=t;i<CGTOT;i+=256) cg_s[i] = cg[i];
  for(int i=t;i<FTOT;i+=256)  f_s[i]  = fa[i];
  __syncthreads();
  #pragma unroll
  for(int L=0; L<4; L++){
    const int KLL = KLc[L], nL = 2*L+1;
    const int nel = nL*KLL;
    for(int e=t; e<nel; e+=256){
      const int M = e / KLL, k = e - M*KLL;
      float acc = 0.f;
      #pragma unroll
      for(int gi=0; gi<LG.cnt[L]; gi++){
        const int ci = LG.list[L][gi];
        const int l1 = CB.l1[ci], l2 = CB.l2[ci];
        if(k < CB.kk[ci]){
          const int n2 = 2*l2+1;
          #pragma unroll
          for(int aa=0; aa<2*l1+1; aa++){
            const float Av = f_s[FBc[l1] + aa*KLc[l1] + k];
            #pragma unroll
            for(int b=0; b<n2; b++)
              acc += cg_s[CB.cgoff[ci] + (aa*n2+b)*nL + M] * (Av * f_s[FBc[l2] + b*KLc[l2] + k]);
          }
        }
      }
      fa[FBc[L] + M*KLL + k] = f_s[FBc[L] + M*KLL + k] + 0.1f*acc;   // NU_SCALING residual
    }
  }
}

// ---------------- equivariant MP v2: S-factorization ----------------
// phase: barrier, dump owned slices to stageT, barrier, contract assigned combos with cg (scalar loads)
template<int G,int PH,int U>
__device__ __forceinline__ void contract_combos(const float* __restrict__ stageT,
    float* __restrict__ out_s, const float* __restrict__ cg, int lane){
  if constexpr (U < CA.cnt[G]) {
    constexpr int ci = CA.ci[G][U];
    if constexpr (combo_in_phase(ci,PH)) {
      constexpr int l1=CB.l1[ci], l2=CB.l2[ci], L=CB.L[ci];
      constexpr int n1=2*l1+1, n2=2*l2+1, nL=2*L+1;
      constexpr int kt=phase_kt(PH);
      constexpr int rbase = rb_base(kt,l1,l2) - phase_rbadj(PH);
      float oa[nL];
      #pragma unroll
      for(int M=0;M<nL;M++) oa[M]=0.f;
      #pragma unroll
      for(int aa=0;aa<n1;aa++){
        #pragma unroll
        for(int b=0;b<n2;b++){
          const float sv = stageT[lane*RPAD + rbase + aa*n2 + b];
          #pragma unroll
          for(int M=0;M<nL;M++)
            oa[M] = fmaf(cg[CB.cgoff[ci] + (aa*n2+b)*nL + M], sv, oa[M]);  // uniform idx -> s_load
        }
      }
      #pragma unroll
      for(int M=0;M<nL;M++)
        atomicAdd(&out_s[FBc[L] + M*KLc[L] + kt*64 + lane], oa[M]);
    }
    contract_combos<G,PH,U+1>(stageT,out_s,cg,lane);
  }
}

template<int G,int PH>
__device__ __forceinline__ void eq_phase(const float* acc, float* stageT, float* out_s,
    const float* __restrict__ cg, int lane){
  __syncthreads();                       // protect previous phase's stage reads
  #pragma unroll
  for(int s=0;s<ET.ns[G];s++){
    if(ET.sph[G][s]==PH) stageT[lane*RPAD + ET.srow[G][s]] = acc[s];
  }
  __syncthreads();
  contract_combos<G,PH,0>(stageT,out_s,cg,lane);
}

template<int G>
__device__ __forceinline__ void eq_group_main(
    const int a, const int t, const int lane,
    const float* __restrict__ sh, const float* __restrict__ rb,
    const float* __restrict__ cemb, const int* __restrict__ nbrs,
    const int* __restrict__ offsets, const int* __restrict__ perm,
    const float* __restrict__ featsA, float* __restrict__ featsB,
    const float* __restrict__ cg,
    float* stageT, float* out_s, float* edge_s, int* nb_s){
  constexpr int NS = ET.ns[G], NR = ET.nr[G];
  float acc[NS];
  #pragma unroll
  for(int s=0;s<NS;s++) acc[s]=0.f;
  for(int i=t;i<FTOT;i+=256) out_s[i]=0.f;
  const int beg = offsets[a], cnt = offsets[a+1]-beg;
  for(int jb=0; jb<cnt; jb+=8){
    __syncthreads();                     // protect edge_s/nb_s reuse
    if(t < 128){
      int j=t>>4, i=t&15;
      if(jb+j<cnt){
        int p = perm[beg+jb+j];
        if(i==0) nb_s[j] = nbrs[p];
        int l = (i==0)?0:(i<4)?1:(i<9)?2:3;
        float s=0.f;
        for(int n=RBBc[l]; n<RBBc[l+1]; n++) s += rb[p*20+n];
        edge_s[j*16+i] = sh[p*16+i]*0.1f*s;    // sh * NU_SCALING * rb.sum
      }
    }
    __syncthreads();
    const int jm = (cnt-jb<8)?(cnt-jb):8;
    for(int j=0;j<jm;j++){
      const int nb = nb_s[j];
      const float ce = cemb[(size_t)nb*32 + (lane&31)];   // embed_centers fused on neighbor
      const float* fp = featsA + (size_t)nb*FTOT + lane;
      float fgv[NR];
      #pragma unroll
      for(int r=0;r<NR;r++) fgv[r] = fp[ET.roff[G][r]] * ce;
      float ed[16];
      #pragma unroll
      for(int q=0;q<4;q++){
        float4 v = *(const float4*)(edge_s + j*16 + q*4);
        ed[q*4]=v.x; ed[q*4+1]=v.y; ed[q*4+2]=v.z; ed[q*4+3]=v.w;
      }
      #pragma unroll
      for(int s=0;s<NS;s++)
        acc[s] = fmaf(ed[ET.eidx[G][s]], fgv[ET.fidx[G][s]], acc[s]);
    }
  }
  eq_phase<G,0>(acc,stageT,out_s,cg,lane);
  eq_phase<G,1>(acc,stageT,out_s,cg,lane);
  eq_phase<G,2>(acc,stageT,out_s,cg,lane);
  eq_phase<G,3>(acc,stageT,out_s,cg,lane);
  eq_phase<G,4>(acc,stageT,out_s,cg,lane);
  __syncthreads();
  float* ob = featsB + (size_t)a*FTOT;
  for(int i=t;i<FTOT;i+=256) ob[i] = 0.1f*out_s[i];       // MP_SCALING
}

__global__ __launch_bounds__(256,3) void k_eq2(const float* __restrict__ sh, const float* __restrict__ rb,
    const float* __restrict__ cemb, const int* __restrict__ nbrs, const int* __restrict__ offsets,
    const int* __restrict__ perm, const float* __restrict__ featsA, float* __restrict__ featsB,
    const float* __restrict__ cg){
  __shared__ float stageT[64*RPAD];   // 38144 B, odd lane stride -> conflict-free
  __shared__ float out_s[FTOT];       // 7680 B
  __shared__ float edge_s[8*16];
  __shared__ int   nb_s[8];
  const int a = blockIdx.x, t = threadIdx.x, lane = t&63, g = t>>6;
  switch(g){  // wave-uniform branch; identical barrier structure in every case
    case 0: eq_group_main<0>(a,t,lane,sh,rb,cemb,nbrs,offsets,perm,featsA,featsB,cg,stageT,out_s,edge_s,nb_s); break;
    case 1: eq_group_main<1>(a,t,lane,sh,rb,cemb,nbrs,offsets,perm,featsA,featsB,cg,stageT,out_s,edge_s,nb_s); break;
    case 2: eq_group_main<2>(a,t,lane,sh,rb,cemb,nbrs,offsets,perm,featsA,featsB,cg,stageT,out_s,edge_s,nb_s); break;
    default: eq_group_main<3>(a,t,lane,sh,rb,cemb,nbrs,offsets,perm,featsA,featsB,cg,stageT,out_s,edge_s,nb_s); break;
  }
}

// ---------------- energy readout ----------------
__global__ __launch_bounds__(256) void k_energy(const float* __restrict__ feats,
    const float* __restrict__ cemb, const float* __restrict__ wE, const float* __restrict__ bE,
    float* __restrict__ out, int N){
  const int wid = threadIdx.x >> 6, lane = threadIdx.x & 63;
  const int a = blockIdx.x*4 + wid;
  if(a >= N) return;
  const float e = cemb[(size_t)a*32 + (lane & 31)];
  float s = 0.f;
  for(int k=lane; k<256; k+=64) s += feats[(size_t)a*FTOT + k] * e * wE[k];
  #pragma unroll
  for(int off=32; off; off>>=1) s += __shfl_down(s, off, 64);
  if(lane == 0) out[a] = s + bE[0];
}

// ---------------- launcher ----------------
extern "C" void kernel_launch(void* const* d_in, const int* in_sizes, int n_in,
                              void* d_out, int out_size, void* d_ws, size_t ws_size,
                              hipStream_t stream){
  const float* sh        = (const float*)d_in[0];
  const float* rb        = (const float*)d_in[1];
  const float* emb_table = (const float*)d_in[2];
  const float* wE        = (const float*)d_in[3];
  const float* bE        = (const float*)d_in[4];
  const int*   species   = (const int*)d_in[5];
  const int*   centers   = (const int*)d_in[6];
  const int*   nbrs      = (const int*)d_in[7];
  const int N = in_sizes[5];
  const int P = in_sizes[6];

  char* ws = (char*)d_ws; size_t off = 0;
  auto carve = [&](size_t bytes)->void*{
    void* p = ws + off; off = (off + bytes + 255) & ~(size_t)255; return p;
  };
  float* cg_d    = (float*)carve((size_t)CGTOT*4);
  float* cemb    = (float*)carve((size_t)N*32*4);
  int*   counts  = (int*)  carve((size_t)N*4);
  int*   offsets = (int*)  carve((size_t)(N+1)*4);
  int*   cursor  = (int*)  carve((size_t)N*4);
  int*   perm    = (int*)  carve((size_t)P*4);
  float* featsA  = (float*)carve((size_t)N*FTOT*4);
  float* featsB  = (float*)carve((size_t)N*FTOT*4);
  (void)ws_size; (void)n_in; (void)out_size;

  static const std::vector<float> cg_host = build_cg();  // deterministic; host-side cache only
  hipMemcpyAsync(cg_d, cg_host.data(), (size_t)CGTOT*4, hipMemcpyHostToDevice, stream);

  k_cemb   <<<(N*32 + 255)/256, 256, 0, stream>>>(emb_table, species, cemb, counts, N);
  k_hist   <<<(P + 255)/256,    256, 0, stream>>>(centers, counts, P);
  k_scan   <<<1,                256, 0, stream>>>(counts, offsets, cursor, N);
  k_scatter<<<(P + 255)/256,    256, 0, stream>>>(centers, cursor, perm, P);
  k_inv    <<<N,                256, 0, stream>>>(sh, rb, cemb, nbrs, offsets, perm, featsA);
  k_tp     <<<N,                256, 0, stream>>>(featsA, cg_d);
  k_eq2    <<<N,                256, 0, stream>>>(sh, rb, cemb, nbrs, offsets, perm, featsA, featsB, cg_d);
  k_tp     <<<N,                256, 0, stream>>>(featsB, cg_d);
  k_energy <<<(N + 3)/4,        256, 0, stream>>>(featsB, cemb, wE, bE, (float*)d_out, N);
}

// Round 3
// 936.244 us; speedup vs baseline: 2.0790x; 1.0311x over previous
//
#include <hip/hip_runtime.h>
#include <vector>
#include <cmath>
#include <cstdint>

// ---------------- static model tables (constexpr, device-usable) ----------------
constexpr int KLc[4]  = {256,192,128,64};     // k_max per l
constexpr int NMLc[4] = {8,6,4,2};            // radial basis per l
constexpr int SHBc[5] = {0,1,4,9,16};         // sh split bases
constexpr int RBBc[5] = {0,8,14,18,20};       // rb split bases
constexpr int FBc[5]  = {0,256,832,1472,1920};// feats flat base per l  (sum (2l+1)*K[l])
constexpr int NCMB = 34, CGTOT = 3436, FTOT = 1920;

struct Combos { int l1[NCMB], l2[NCMB], L[NCMB], cgoff[NCMB], kk[NCMB]; };
constexpr Combos make_combos(){
  Combos c{}; int n=0, cg=0;
  for(int a=0;a<=3;a++)for(int b=0;b<=3;b++){
    int lo=a>b?a-b:b-a, hi=(a+b<3)?(a+b):3;
    for(int L=lo;L<=hi;L++){
      c.l1[n]=a; c.l2[n]=b; c.L[n]=L; c.cgoff[n]=cg;
      int mx=a>b?a:b; if(L>mx) mx=L; c.kk[n]=KLc[mx];          // TP truncation (min of all three)
      cg+=(2*a+1)*(2*b+1)*(2*L+1); n++;
    }
  }
  return c;
}
constexpr Combos CB = make_combos();
static_assert(CB.cgoff[NCMB-1] + 7*7*7 == CGTOT, "cg size");

struct Grp { int cnt[4]; int list[4][12]; };
constexpr Grp make_Lg(){ Grp g{}; for(int i=0;i<NCMB;i++){ int L=CB.L[i]; g.list[L][g.cnt[L]++]=i; } return g; }
constexpr Grp LG = make_Lg();     // combos grouped by output L (for k_tp)

struct Rows { int sh[64], rb[64], off[64]; };
constexpr Rows make_rows(){ Rows r{}; int i=0;
  for(int l=0;l<4;l++)for(int m=0;m<2*l+1;m++)for(int n=0;n<NMLc[l];n++){
    r.sh[i]=SHBc[l]+m; r.rb[i]=RBBc[l]+n; r.off[i]=FBc[l]+m*KLc[l]+n*32; i++; }
  for(;i<64;i++){ r.sh[i]=0; r.rb[i]=0; r.off[i]=0; }
  return r; }
constexpr Rows RWS = make_rows();  // 60 (l,m,n) rows for invariant MP

// ---------------- k_eq tables: S-factorization slices, 8 wave-groups ----------------
// S[l1,a,l2,b][k] = sum_pairs edge[l1,a] * femb[l2,b,k]; slice unit = (l1,a,l2,b,ktile)
// Slice valid iff l2 <= 3-kt && |l1-l2| <= 3-kt   (equivariant kk = min(K[l2],K[L]), L>=|l1-l2|)
constexpr int NSL=425, NG=8, MAXS=56, MAXR=12, RPAD=149; // RPAD odd -> 2-way bank aliasing (free)

constexpr int iabs_(int x){ return x<0?-x:x; }
__host__ __device__ constexpr bool sl_valid(int l1,int l2,int kt){ return l2<=3-kt && iabs_(l1-l2)<=3-kt; }

__host__ __device__ constexpr int rb_base(int kt,int l1,int l2){
  int base=0;
  for(int p=0;p<4;p++)for(int q=0;q<4;q++){
    if(p==l1 && q==l2) return base;
    if(sl_valid(p,q,kt)) base += (2*p+1)*(2*q+1);
  }
  return base;
}

struct EqTab {
  int ns[NG];
  unsigned char eidx[NG][MAXS];   // edge register index (SHB[l1]+a)
  unsigned char fidx[NG][MAXS];   // fg register index within group
  short         srow[NG][MAXS];   // stage row within its dump phase
  unsigned char sph [NG][MAXS];   // dump phase 0..4
  int nr[NG];
  short roff[NG][MAXR];           // fg row offsets into feats (element units)
  int total;
};
constexpr EqTab make_eqtab(){
  EqTab T{}; int gidx=0;
  for(int l2=0;l2<4;l2++)for(int kt=0;kt<4-l2;kt++)for(int b=0;b<2*l2+1;b++){
    const int rowoff = FBc[l2] + b*KLc[l2] + kt*64;
    for(int l1=0;l1<4;l1++){
      if(!sl_valid(l1,l2,kt)) continue;
      for(int a=0;a<2*l1+1;a++){
        int g = (gidx*NG)/NSL;
        int s = T.ns[g]++;
        T.eidx[g][s] = (unsigned char)(SHBc[l1]+a);
        int rbi = rb_base(kt,l1,l2) + a*(2*l2+1) + b;
        int ph, sr;
        if(kt==0){ if(l1<=2){ ph=0; sr=rbi; } else { ph=1; sr=rbi-144; } }
        else { ph=kt+1; sr=rbi; }
        T.sph[g][s]=(unsigned char)ph; T.srow[g][s]=(short)sr;
        int ri=-1;
        for(int r=0;r<T.nr[g];r++) if(T.roff[g][r]==(short)rowoff) ri=r;
        if(ri<0){ ri=T.nr[g]; T.roff[g][T.nr[g]++]=(short)rowoff; }
        T.fidx[g][s]=(unsigned char)ri;
        gidx++;
      }
    }
  }
  T.total=gidx;
  return T;
}
constexpr EqTab ET = make_eqtab();
static_assert(ET.total==NSL, "slice count");
constexpr bool chk_ns(){ for(int g=0;g<NG;g++) if(ET.ns[g]>MAXS) return false; return true; }
constexpr bool chk_nr(){ for(int g=0;g<NG;g++) if(ET.nr[g]>MAXR) return false; return true; }
static_assert(chk_ns(), "MAXS");
static_assert(chk_nr(), "MAXR");

// contraction combo -> group assignment (greedy by cost n1*n2*nL)
struct CAsg { int cnt[NG]; unsigned char ci[NG][8]; };
constexpr CAsg make_casg(){
  CAsg C{}; bool used[NCMB]{}; int load[NG]{};
  for(int it=0; it<NCMB; it++){
    int best=-1, bc=-1;
    for(int i=0;i<NCMB;i++) if(!used[i]){
      int c=(2*CB.l1[i]+1)*(2*CB.l2[i]+1)*(2*CB.L[i]+1);
      if(c>bc){bc=c;best=i;}
    }
    used[best]=true;
    int g=0; for(int j=1;j<NG;j++) if(load[j]<load[g]) g=j;
    C.ci[g][C.cnt[g]++]=(unsigned char)best; load[g]+=bc;
  }
  return C;
}
constexpr CAsg CA = make_casg();
constexpr bool chk_ca(){ for(int g=0;g<NG;g++) if(CA.cnt[g]>8) return false; return true; }
static_assert(chk_ca(), "CA cap");

__host__ __device__ constexpr bool combo_in_phase(int ci,int ph){
  int l1=CB.l1[ci], l2=CB.l2[ci], L=CB.L[ci];
  if(ph==0) return l1<=2;
  if(ph==1) return l1==3;
  int kt=ph-1;
  return (l2<=3-kt) && (L<=3-kt);
}
__host__ __device__ constexpr int phase_kt(int ph){ return ph<=1?0:ph-1; }
__host__ __device__ constexpr int phase_rbadj(int ph){ return ph==1?144:0; }

// ---------------- host: numpy-legacy RandomState(0) CG generation ----------------
namespace nprng {
struct MT {
  uint32_t mt[624]; int mti; bool has_g; double g;
  void seed(uint32_t s){ for(int i=0;i<624;i++){ mt[i]=s; s=1812433253u*(s^(s>>30))+(uint32_t)i+1u; } mti=624; has_g=false; g=0.0; }
  uint32_t u32(){
    if(mti>=624){
      for(int i=0;i<624;i++){
        uint32_t y=(mt[i]&0x80000000u)|(mt[(i+1)%624]&0x7fffffffu);
        mt[i]=mt[(i+397)%624]^(y>>1)^((y&1u)?0x9908b0dfu:0u);
      }
      mti=0;
    }
    uint32_t y=mt[mti++];
    y^=y>>11; y^=(y<<7)&0x9d2c5680u; y^=(y<<15)&0xefc60000u; y^=y>>18;
    return y;
  }
  double dbl(){ uint32_t a=u32()>>5, b=u32()>>6; return (a*67108864.0+b)/9007199254740992.0; }
  double gauss(){
    if(has_g){ has_g=false; return g; }
    double f,x1,x2,r2;
    do{ x1=2.0*dbl()-1.0; x2=2.0*dbl()-1.0; r2=x1*x1+x2*x2; }while(r2>=1.0||r2==0.0);
    f=sqrt(-2.0*log(r2)/r2);
    g=f*x1; has_g=true; return f*x2;
  }
};
}
static std::vector<float> build_cg(){
  nprng::MT r; r.seed(0);
  std::vector<float> v; v.reserve(CGTOT);
  for(int l1=0;l1<=3;l1++)for(int l2=0;l2<=3;l2++){
    int lo = l1>l2? l1-l2 : l2-l1;
    int hi = (l1+l2<3)? (l1+l2) : 3;
    for(int L=lo;L<=hi;L++){
      int n=(2*l1+1)*(2*l2+1)*(2*L+1);
      for(int i=0;i<n;i++) v.push_back((float)(r.gauss()*0.2));
    }
  }
  return v;
}

// ---------------- small setup kernels ----------------
__global__ __launch_bounds__(256) void k_cemb(const float* __restrict__ emb_table,
    const int* __restrict__ species, float* __restrict__ cemb, int* __restrict__ counts, int N){
  int i = blockIdx.x*256 + threadIdx.x;
  if(i < N) counts[i] = 0;
  if(i < N*32){ int n = i>>5, c = i&31; cemb[i] = emb_table[species[n]*32 + c]; }
}

__global__ __launch_bounds__(256) void k_hist(const int* __restrict__ centers, int* counts, int P){
  int i = blockIdx.x*256 + threadIdx.x;
  if(i < P) atomicAdd(&counts[centers[i]], 1);
}

__global__ __launch_bounds__(256) void k_scan(const int* __restrict__ counts,
    int* __restrict__ offsets, int* __restrict__ cursor, int N){
  __shared__ int part[256];
  const int t = threadIdx.x;
  const int CH = (N + 255)/256;
  const int lo = t*CH;
  int hi = (t+1)*CH; if(hi > N) hi = N;
  int s = 0;
  for(int i=lo;i<hi;i++) s += counts[i];
  part[t] = s; __syncthreads();
  const int own = s;
  for(int d=1; d<256; d<<=1){
    int v = (t>=d)? part[t-d] : 0;
    __syncthreads();
    part[t] += v;
    __syncthreads();
  }
  int run = part[t] - own;
  for(int i=lo;i<hi;i++){ offsets[i]=run; cursor[i]=run; run += counts[i]; }
  if(t==255) offsets[N] = part[255];
}

__global__ __launch_bounds__(256) void k_scatter(const int* __restrict__ centers,
    int* cursor, int* __restrict__ perm, int P){
  int i = blockIdx.x*256 + threadIdx.x;
  if(i < P){ int c = centers[i]; int pos = atomicAdd(&cursor[c], 1); perm[pos] = i; }
}

// ---------------- invariant MP (batched pairs, 3 barriers / 8 pairs) ----------------
__global__ __launch_bounds__(256) void k_inv(const float* __restrict__ sh, const float* __restrict__ rb,
    const float* __restrict__ cemb, const int* __restrict__ nbrs, const int* __restrict__ offsets,
    const int* __restrict__ perm, float* __restrict__ feats){
  const int a = blockIdx.x, t = threadIdx.x;
  __shared__ float sh_s[8][16], rb_s[8][20], emb_s[8][32], shrb_s[8][60];
  const int c = t & 31, rg = t >> 5;
  float acc[8];
  #pragma unroll
  for(int j=0;j<8;j++) acc[j] = 0.f;
  const int beg = offsets[a], cnt = offsets[a+1]-beg;
  for(int jb=0; jb<cnt; jb+=8){
    __syncthreads();
    for(int u=t; u<8*36; u+=256){
      int j=u/36, i=u-36*j;
      if(jb+j<cnt){
        int p=perm[beg+jb+j];
        if(i<16) sh_s[j][i]=sh[p*16+i]*0.1f;      // NU_SCALING
        else     rb_s[j][i-16]=rb[p*20+i-16];
      }
    }
    for(int u=t; u<8*32; u+=256){
      int j=u>>5, i=u&31;
      if(jb+j<cnt){ int nb=nbrs[perm[beg+jb+j]]; emb_s[j][i]=cemb[(size_t)nb*32+i]; }
    }
    __syncthreads();
    for(int u=t; u<8*60; u+=256){
      int j=u/60, r=u-60*j;
      if(jb+j<cnt) shrb_s[j][r] = sh_s[j][RWS.sh[r]] * rb_s[j][RWS.rb[r]];
    }
    __syncthreads();
    const int jm = (cnt-jb<8)?(cnt-jb):8;
    for(int j=0;j<jm;j++){
      const float e = emb_s[j][c];
      #pragma unroll
      for(int q=0;q<8;q++){ int r=rg+8*q; if(r<60) acc[q]=fmaf(shrb_s[j][r], e, acc[q]); }
    }
  }
  #pragma unroll
  for(int q=0;q<8;q++){
    int r = rg + 8*q;
    if(r < 60) feats[(size_t)a*FTOT + RWS.off[r] + c] = 0.1f * acc[q];  // MP_SCALING
  }
}

// ---------------- CG iterate (in-place): feats = feats + 0.1 * TP(feats, feats) ----------------
// cg index is wave-uniform everywhere (all M/k boundaries 64-aligned) -> scalar loads
__device__ __forceinline__ float cg_u(const float* __restrict__ cg, int idx){
  return cg[__builtin_amdgcn_readfirstlane(idx)];
}
__global__ __launch_bounds__(256) void k_tp(float* __restrict__ feats, const float* __restrict__ cg){
  const int a = blockIdx.x, t = threadIdx.x;
  __shared__ float f_s[FTOT];
  float* fa = feats + (size_t)a*FTOT;
  for(int i=t;i<FTOT;i+=256)  f_s[i]  = fa[i];
  __syncthreads();
  #pragma unroll
  for(int L=0; L<4; L++){
    const int KLL = KLc[L], nL = 2*L+1;
    const int nel = nL*KLL;
    for(int e=t; e<nel; e+=256){
      const int M = e / KLL, k = e - M*KLL;
      float acc = 0.f;
      #pragma unroll
      for(int gi=0; gi<LG.cnt[L]; gi++){
        const int ci = LG.list[L][gi];
        const int l1 = CB.l1[ci], l2 = CB.l2[ci];
        if(k < CB.kk[ci]){
          const int n2 = 2*l2+1;
          #pragma unroll
          for(int aa=0; aa<2*l1+1; aa++){
            const float Av = f_s[FBc[l1] + aa*KLc[l1] + k];
            #pragma unroll
            for(int b=0; b<n2; b++)
              acc += cg_u(cg, CB.cgoff[ci] + (aa*n2+b)*nL + M) * (Av * f_s[FBc[l2] + b*KLc[l2] + k]);
          }
        }
      }
      fa[FBc[L] + M*KLL + k] = f_s[FBc[L] + M*KLL + k] + 0.1f*acc;   // NU_SCALING residual
    }
  }
}

// ---------------- equivariant MP v3: S-factorization, 8 waves, pair prefetch ----------------
template<int G,int PH,int U>
__device__ __forceinline__ void contract_combos(const float* __restrict__ stageT,
    float* __restrict__ out_s, const float* __restrict__ cg, int lane){
  if constexpr (U < CA.cnt[G]) {
    constexpr int ci = CA.ci[G][U];
    if constexpr (combo_in_phase(ci,PH)) {
      constexpr int l1=CB.l1[ci], l2=CB.l2[ci], L=CB.L[ci];
      constexpr int n1=2*l1+1, n2=2*l2+1, nL=2*L+1;
      constexpr int kt=phase_kt(PH);
      constexpr int rbase = rb_base(kt,l1,l2) - phase_rbadj(PH);
      float oa[nL];
      #pragma unroll
      for(int M=0;M<nL;M++) oa[M]=0.f;
      #pragma unroll
      for(int aa=0;aa<n1;aa++){
        #pragma unroll
        for(int b=0;b<n2;b++){
          const float sv = stageT[lane*RPAD + rbase + aa*n2 + b];
          #pragma unroll
          for(int M=0;M<nL;M++)
            oa[M] = fmaf(cg[CB.cgoff[ci] + (aa*n2+b)*nL + M], sv, oa[M]);  // uniform idx -> s_load
        }
      }
      #pragma unroll
      for(int M=0;M<nL;M++)
        atomicAdd(&out_s[FBc[L] + M*KLc[L] + kt*64 + lane], oa[M]);
    }
    contract_combos<G,PH,U+1>(stageT,out_s,cg,lane);
  }
}

template<int G,int PH>
__device__ __forceinline__ void eq_phase(const float* acc, float* stageT, float* out_s,
    const float* __restrict__ cg, int lane){
  __syncthreads();                       // protect previous phase's stage reads
  #pragma unroll
  for(int s=0;s<ET.ns[G];s++){
    if(ET.sph[G][s]==PH) stageT[lane*RPAD + ET.srow[G][s]] = acc[s];
  }
  __syncthreads();
  contract_combos<G,PH,0>(stageT,out_s,cg,lane);
}

template<int G>
__device__ __forceinline__ void eq_group_main(
    const int a, const int t, const int lane,
    const float* __restrict__ sh, const float* __restrict__ rb,
    const float* __restrict__ cemb, const int* __restrict__ nbrs,
    const int* __restrict__ offsets, const int* __restrict__ perm,
    const float* __restrict__ featsA, float* __restrict__ featsB,
    const float* __restrict__ cg,
    float* stageT, float* out_s, float* edge_s, int* nb_s){
  constexpr int NS = ET.ns[G], NR = ET.nr[G];
  float acc[NS];
  #pragma unroll
  for(int s=0;s<NS;s++) acc[s]=0.f;
  for(int i=t;i<FTOT;i+=512) out_s[i]=0.f;
  const int beg = offsets[a], cnt = offsets[a+1]-beg;
  // prime the prefetch pipeline with pair 0 (directly from global)
  float fg_c[NR], ce_c = 0.f;
  if(cnt > 0){
    const int nb0 = nbrs[perm[beg]];
    ce_c = cemb[(size_t)nb0*32 + (lane&31)];
    const float* fp = featsA + (size_t)nb0*FTOT + lane;
    #pragma unroll
    for(int r=0;r<NR;r++) fg_c[r] = fp[ET.roff[G][r]];
  }
  for(int jb=0; jb<cnt; jb+=16){
    __syncthreads();                     // protect edge_s/nb_s reuse
    if(t < 256){
      int j=t>>4, i=t&15;
      if(jb+j<cnt){
        int p = perm[beg+jb+j];
        if(i==0) nb_s[j] = nbrs[p];
        int l = (i==0)?0:(i<4)?1:(i<9)?2:3;
        float s=0.f;
        for(int n=RBBc[l]; n<RBBc[l+1]; n++) s += rb[p*20+n];
        edge_s[j*16+i] = sh[p*16+i]*0.1f*s;    // sh * NU_SCALING * rb.sum
      }
    }
    __syncthreads();
    const int jm = (cnt-jb<16)?(cnt-jb):16;
    for(int j=0;j<jm;j++){
      // issue next pair's gather before this pair's FMA chain
      int nb_n = 0; bool have_n = true;
      if(j+1 < jm)            nb_n = nb_s[j+1];
      else if(jb+16 < cnt)    nb_n = nbrs[perm[beg+jb+16]];  // first pair of next batch
      else                    have_n = false;
      float fg_n[NR], ce_n = 0.f;
      {
        const int nbl = have_n ? nb_n : 0;
        ce_n = cemb[(size_t)nbl*32 + (lane&31)];
        const float* fp = featsA + (size_t)nbl*FTOT + lane;
        #pragma unroll
        for(int r=0;r<NR;r++) fg_n[r] = fp[ET.roff[G][r]];
      }
      // edge components (LDS broadcast) + premultiply embedding
      float ed[16];
      #pragma unroll
      for(int q=0;q<4;q++){
        float4 v = *(const float4*)(edge_s + j*16 + q*4);
        ed[q*4]=v.x; ed[q*4+1]=v.y; ed[q*4+2]=v.z; ed[q*4+3]=v.w;
      }
      float fgc[NR];
      #pragma unroll
      for(int r=0;r<NR;r++) fgc[r] = fg_c[r]*ce_c;
      #pragma unroll
      for(int s=0;s<NS;s++)
        acc[s] = fmaf(ed[ET.eidx[G][s]], fgc[ET.fidx[G][s]], acc[s]);
      #pragma unroll
      for(int r=0;r<NR;r++) fg_c[r] = fg_n[r];
      ce_c = ce_n;
    }
  }
  eq_phase<G,0>(acc,stageT,out_s,cg,lane);
  eq_phase<G,1>(acc,stageT,out_s,cg,lane);
  eq_phase<G,2>(acc,stageT,out_s,cg,lane);
  eq_phase<G,3>(acc,stageT,out_s,cg,lane);
  eq_phase<G,4>(acc,stageT,out_s,cg,lane);
  __syncthreads();
  float* ob = featsB + (size_t)a*FTOT;
  for(int i=t;i<FTOT;i+=512) ob[i] = 0.1f*out_s[i];       // MP_SCALING
}

__global__ __launch_bounds__(512,4) void k_eq2(const float* __restrict__ sh, const float* __restrict__ rb,
    const float* __restrict__ cemb, const int* __restrict__ nbrs, const int* __restrict__ offsets,
    const int* __restrict__ perm, const float* __restrict__ featsA, float* __restrict__ featsB,
    const float* __restrict__ cg){
  __shared__ float stageT[64*RPAD];   // 38144 B, odd lane stride -> conflict-free
  __shared__ float out_s[FTOT];       // 7680 B
  __shared__ float edge_s[16*16];
  __shared__ int   nb_s[16];
  const int a = blockIdx.x, t = threadIdx.x, lane = t&63, g = t>>6;
  switch(g){  // wave-uniform branch; identical barrier structure in every case
    case 0: eq_group_main<0>(a,t,lane,sh,rb,cemb,nbrs,offsets,perm,featsA,featsB,cg,stageT,out_s,edge_s,nb_s); break;
    case 1: eq_group_main<1>(a,t,lane,sh,rb,cemb,nbrs,offsets,perm,featsA,featsB,cg,stageT,out_s,edge_s,nb_s); break;
    case 2: eq_group_main<2>(a,t,lane,sh,rb,cemb,nbrs,offsets,perm,featsA,featsB,cg,stageT,out_s,edge_s,nb_s); break;
    case 3: eq_group_main<3>(a,t,lane,sh,rb,cemb,nbrs,offsets,perm,featsA,featsB,cg,stageT,out_s,edge_s,nb_s); break;
    case 4: eq_group_main<4>(a,t,lane,sh,rb,cemb,nbrs,offsets,perm,featsA,featsB,cg,stageT,out_s,edge_s,nb_s); break;
    case 5: eq_group_main<5>(a,t,lane,sh,rb,cemb,nbrs,offsets,perm,featsA,featsB,cg,stageT,out_s,edge_s,nb_s); break;
    case 6: eq_group_main<6>(a,t,lane,sh,rb,cemb,nbrs,offsets,perm,featsA,featsB,cg,stageT,out_s,edge_s,nb_s); break;
    default: eq_group_main<7>(a,t,lane,sh,rb,cemb,nbrs,offsets,perm,featsA,featsB,cg,stageT,out_s,edge_s,nb_s); break;
  }
}

// ---------------- energy readout ----------------
__global__ __launch_bounds__(256) void k_energy(const float* __restrict__ feats,
    const float* __restrict__ cemb, const float* __restrict__ wE, const float* __restrict__ bE,
    float* __restrict__ out, int N){
  const int wid = threadIdx.x >> 6, lane = threadIdx.x & 63;
  const int a = blockIdx.x*4 + wid;
  if(a >= N) return;
  const float e = cemb[(size_t)a*32 + (lane & 31)];
  float s = 0.f;
  for(int k=lane; k<256; k+=64) s += feats[(size_t)a*FTOT + k] * e * wE[k];
  #pragma unroll
  for(int off=32; off; off>>=1) s += __shfl_down(s, off, 64);
  if(lane == 0) out[a] = s + bE[0];
}

// ---------------- launcher ----------------
extern "C" void kernel_launch(void* const* d_in, const int* in_sizes, int n_in,
                              void* d_out, int out_size, void* d_ws, size_t ws_size,
                              hipStream_t stream){
  const float* sh        = (const float*)d_in[0];
  const float* rb        = (const float*)d_in[1];
  const float* emb_table = (const float*)d_in[2];
  const float* wE        = (const float*)d_in[3];
  const float* bE        = (const float*)d_in[4];
  const int*   species   = (const int*)d_in[5];
  const int*   centers   = (const int*)d_in[6];
  const int*   nbrs      = (const int*)d_in[7];
  const int N = in_sizes[5];
  const int P = in_sizes[6];

  char* ws = (char*)d_ws; size_t off = 0;
  auto carve = [&](size_t bytes)->void*{
    void* p = ws + off; off = (off + bytes + 255) & ~(size_t)255; return p;
  };
  float* cg_d    = (float*)carve((size_t)CGTOT*4);
  float* cemb    = (float*)carve((size_t)N*32*4);
  int*   counts  = (int*)  carve((size_t)N*4);
  int*   offsets = (int*)  carve((size_t)(N+1)*4);
  int*   cursor  = (int*)  carve((size_t)N*4);
  int*   perm    = (int*)  carve((size_t)P*4);
  float* featsA  = (float*)carve((size_t)N*FTOT*4);
  float* featsB  = (float*)carve((size_t)N*FTOT*4);
  (void)ws_size; (void)n_in; (void)out_size;

  static const std::vector<float> cg_host = build_cg();  // deterministic; host-side cache only
  hipMemcpyAsync(cg_d, cg_host.data(), (size_t)CGTOT*4, hipMemcpyHostToDevice, stream);

  k_cemb   <<<(N*32 + 255)/256, 256, 0, stream>>>(emb_table, species, cemb, counts, N);
  k_hist   <<<(P + 255)/256,    256, 0, stream>>>(centers, counts, P);
  k_scan   <<<1,                256, 0, stream>>>(counts, offsets, cursor, N);
  k_scatter<<<(P + 255)/256,    256, 0, stream>>>(centers, cursor, perm, P);
  k_inv    <<<N,                256, 0, stream>>>(sh, rb, cemb, nbrs, offsets, perm, featsA);
  k_tp     <<<N,                256, 0, stream>>>(featsA, cg_d);
  k_eq2    <<<N,                512, 0, stream>>>(sh, rb, cemb, nbrs, offsets, perm, featsA, featsB, cg_d);
  k_tp     <<<N,                256, 0, stream>>>(featsB, cg_d);
  k_energy <<<(N + 3)/4,        256, 0, stream>>>(featsB, cemb, wE, bE, (float*)d_out, N);
}